// Round 9
// baseline (85.008 us; speedup 1.0000x reference)
//
#include <hip/hip_runtime.h>
#include <math.h>

#define BB 16
#define CC 80
#define HW (128*128)
#define N1 (CC*HW)          // 1,310,720 elements per batch per map
#define KK 128
#define FEPS 1e-4f
#define FB2 64              // blocks per (batch, map) plane
#define NJ 10               // j-iterations; 2 float4 per array per thread per j

typedef float f4 __attribute__((ext_vector_type(4)));   // native vec for nt-load

// ws layout (floats):
// [m*48 + 0  + b]  A  (pos_loss / -ln2)
// [m*48 + 16 + b]  B  (neg_loss / -ln2)
// [m*48 + 32 + b]  n  (pos count)
// [96] off_tl [97] off_br [98] mask_sum [99] pull [100] push [104] ticket

__device__ __forceinline__ void proc(float tt, float xx,
                                     float& A, float& B, float& cnt)
{
    const float NLOG2E = -1.4426950408889634f;
    float z  = xx * NLOG2E;                 // -x*log2(e)
    float e  = exp2f(z);                    // e^-x          (v_exp_f32)
    float s  = 1.0f + e;
    float L  = __log2f(s);                  // log2(1+e^-x)  (v_log_f32)
    float p  = __builtin_amdgcn_rcpf(s);    // sigmoid(x)    (v_rcp_f32)
    float ep = e * p;                       // 1-p
    float a  = ep * ep * L;                 // (1-p)^2 * log2(1/p)
    float u  = 1.0f - tt;
    float u2 = u * u;
    float pw = p * u2;                      // p*(1-t)^2
    float bv = pw * pw * (L - z);           // (1-t)^4 p^2 log2(1/(1-p)); ==0 at t==1
    B += bv;
    bool pos = (tt == 1.0f);
    A   += pos ? a : 0.0f;
    cnt += pos ? 1.0f : 0.0f;
}

__global__ __launch_bounds__(256, 8) void focal_kernel(
    const float* __restrict__ t_tl, const float* __restrict__ t_br,
    const float* __restrict__ x_tl, const float* __restrict__ x_br,
    float* __restrict__ ws)
{
    const int m = blockIdx.z;
    const int b = blockIdx.y;
    const f4* __restrict__ T4 = (const f4*)((m ? t_br : t_tl) + (size_t)b * N1);
    const f4* __restrict__ X4 = (const f4*)((m ? x_br : x_tl) + (size_t)b * N1);

    const int JS = FB2 * 512;                       // 32768 float4 per j-step
    const int p0 = blockIdx.x * 512 + threadIdx.x;  // pos 0; pos 1 = p0+256

    f4 ct0 = __builtin_nontemporal_load(T4 + p0);
    f4 cx0 = __builtin_nontemporal_load(X4 + p0);
    f4 ct1 = __builtin_nontemporal_load(T4 + p0 + 256);
    f4 cx1 = __builtin_nontemporal_load(X4 + p0 + 256);

    float A = 0.0f, B = 0.0f, cnt = 0.0f;
    #pragma unroll
    for (int j = 0; j < NJ; ++j) {
        f4 nt0, nx0, nt1, nx1;
        if (j + 1 < NJ) {
            const int q = p0 + (j + 1) * JS;
            nt0 = __builtin_nontemporal_load(T4 + q);
            nx0 = __builtin_nontemporal_load(X4 + q);
            nt1 = __builtin_nontemporal_load(T4 + q + 256);
            nx1 = __builtin_nontemporal_load(X4 + q + 256);
        }
        #pragma unroll
        for (int c = 0; c < 4; ++c) proc(ct0[c], cx0[c], A, B, cnt);
        #pragma unroll
        for (int c = 0; c < 4; ++c) proc(ct1[c], cx1[c], A, B, cnt);
        ct0 = nt0; cx0 = nx0; ct1 = nt1; cx1 = nx1;
    }

    #pragma unroll
    for (int off = 32; off > 0; off >>= 1) {
        A   += __shfl_down(A  , off, 64);
        B   += __shfl_down(B  , off, 64);
        cnt += __shfl_down(cnt, off, 64);
    }
    __shared__ float red[3][4];
    const int lane = threadIdx.x & 63, wv = threadIdx.x >> 6;
    if (lane == 0) { red[0][wv] = A; red[1][wv] = B; red[2][wv] = cnt; }
    __syncthreads();
    if (threadIdx.x == 0) {
        atomicAdd(&ws[m*48 +  0 + b], red[0][0] + red[0][1] + red[0][2] + red[0][3]);
        atomicAdd(&ws[m*48 + 16 + b], red[1][0] + red[1][1] + red[1][2] + red[1][3]);
        atomicAdd(&ws[m*48 + 32 + b], red[2][0] + red[2][1] + red[2][2] + red[2][3]);
    }
}

// off-loss + triplet fused; last finishing block also runs the finalize.
__global__ void small_kernel(
    const float* __restrict__ to_tl, const float* __restrict__ to_br,
    const float* __restrict__ po_tl, const float* __restrict__ po_br,
    const float* __restrict__ e_tl,  const float* __restrict__ e_br,
    const int* __restrict__ idx_tl,  const int* __restrict__ idx_br,
    const int* __restrict__ mask,    float* __restrict__ ws,
    float* __restrict__ out)
{
    const int b = blockIdx.x, k = threadIdx.x;
    const int lane = threadIdx.x & 63, wv = threadIdx.x >> 6;

    float mf = (float)mask[b*KK + k];
    const int itl = idx_tl[b*KK + k];
    const int ibr = idx_br[b*KK + k];

    // ---- offset loss partials ----
    float s_tl = 0.0f, s_br = 0.0f;
    #pragma unroll
    for (int ch = 0; ch < 2; ++ch) {
        float pv = po_tl[((size_t)b*2 + ch)*HW + itl];
        float tv = to_tl[(b*KK + k)*2 + ch];
        float d = pv - tv, ad = fabsf(d);
        s_tl += (ad < 1.0f) ? 0.5f*d*d : (ad - 0.5f);
        pv = po_br[((size_t)b*2 + ch)*HW + ibr];
        tv = to_br[(b*KK + k)*2 + ch];
        d = pv - tv; ad = fabsf(d);
        s_br += (ad < 1.0f) ? 0.5f*d*d : (ad - 0.5f);
    }
    s_tl *= mf; s_br *= mf;

    // ---- triplet ----
    __shared__ float ek_s[KK], mf_s[KK], nred[2];
    float tl = e_tl[(size_t)b*HW + itl];
    float br = e_br[(size_t)b*HW + ibr];
    float ek = 0.5f * (tl + br);
    ek_s[k] = ek; mf_s[k] = mf;

    float nm = mf;
    #pragma unroll
    for (int off = 32; off > 0; off >>= 1) nm += __shfl_down(nm, off, 64);
    if (lane == 0) nred[wv] = nm;
    __syncthreads();
    const float num  = nred[0] + nred[1];
    const float inv  = 1.0f / (num + FEPS);
    const float num2 = (num - 1.0f) * num;
    const float inv2 = 1.0f / (num2 + FEPS);

    float pull = ((tl-ek)*(tl-ek) + (br-ek)*(br-ek)) * inv * mf;

    float push = 0.0f;
    if (mf == 1.0f) {
        for (int j = 0; j < KK; ++j) {
            if (mf_s[j] == 1.0f) {
                float d = fabsf(ek_s[j] - ek);
                push += (fmaxf(2.0f - d, 0.0f) - 2.0f * inv) * inv2;
            }
        }
    }

    #pragma unroll
    for (int off = 32; off > 0; off >>= 1) {
        s_tl += __shfl_down(s_tl, off, 64);
        s_br += __shfl_down(s_br, off, 64);
        mf   += __shfl_down(mf  , off, 64);
        pull += __shfl_down(pull, off, 64);
        push += __shfl_down(push, off, 64);
    }
    __shared__ float r[5][2];
    __shared__ int last_flag;
    if (lane == 0) {
        r[0][wv] = s_tl; r[1][wv] = s_br; r[2][wv] = mf;
        r[3][wv] = pull; r[4][wv] = push;
    }
    __syncthreads();
    if (threadIdx.x == 0) {
        atomicAdd(&ws[96],  r[0][0] + r[0][1]);
        atomicAdd(&ws[97],  r[1][0] + r[1][1]);
        atomicAdd(&ws[98],  r[2][0] + r[2][1]);
        atomicAdd(&ws[99],  r[3][0] + r[3][1]);
        atomicAdd(&ws[100], r[4][0] + r[4][1]);
        __threadfence();
        unsigned old = atomicAdd((unsigned*)&ws[104], 1u);
        last_flag = (old == BB - 1) ? 1 : 0;
    }
    __syncthreads();

    if (last_flag) {
        // coherent read of all partials via atomic-read (cross-XCD safe)
        __shared__ float wsv[101];
        if (k < 101) wsv[k] = atomicAdd(&ws[k], 0.0f);
        __syncthreads();
        if (threadIdx.x == 0) {
            const float NLN2 = -0.6931471805599453f;
            float det = 0.0f;
            for (int m = 0; m < 2; ++m) {
                float f = 0.0f;
                for (int bb = 0; bb < BB; ++bb) {
                    float pos = NLN2 * wsv[m*48 +  0 + bb];
                    float neg = NLN2 * wsv[m*48 + 16 + bb];
                    float n   = wsv[m*48 + 32 + bb];
                    float per = (n == 0.0f) ? neg : (pos + neg) / n;
                    f -= per;
                }
                det += 0.5f * f;
            }
            float numoff = wsv[98] * 2.0f;
            float off = wsv[96] / (numoff + FEPS) + wsv[97] / (numoff + FEPS);
            out[0] = (det + wsv[99] + wsv[100] + off) / (float)BB;
        }
    }
}

extern "C" void kernel_launch(void* const* d_in, const int* in_sizes, int n_in,
                              void* d_out, int out_size, void* d_ws, size_t ws_size,
                              hipStream_t stream) {
    const float* t_tl  = (const float*)d_in[0];
    const float* t_br  = (const float*)d_in[1];
    const float* to_tl = (const float*)d_in[2];
    const float* to_br = (const float*)d_in[3];
    const float* x_tl  = (const float*)d_in[4];
    const float* x_br  = (const float*)d_in[5];
    const float* po_tl = (const float*)d_in[6];
    const float* po_br = (const float*)d_in[7];
    const float* e_tl  = (const float*)d_in[8];
    const float* e_br  = (const float*)d_in[9];
    const int* idx_tl  = (const int*)d_in[10];
    const int* idx_br  = (const int*)d_in[11];
    const int* mask    = (const int*)d_in[12];
    float* ws = (float*)d_ws;

    (void)hipMemsetAsync(ws, 0, 512, stream);
    focal_kernel<<<dim3(FB2, BB, 2), 256, 0, stream>>>(t_tl, t_br, x_tl, x_br, ws);
    small_kernel<<<BB, KK, 0, stream>>>(to_tl, to_br, po_tl, po_br, e_tl, e_br,
                                        idx_tl, idx_br, mask, ws, (float*)d_out);
}

// Round 10
// 82.536 us; speedup vs baseline: 1.0300x; 1.0300x over previous
//
#include <hip/hip_runtime.h>
#include <math.h>

#define BB 16
#define CC 80
#define HW (128*128)
#define N1 (CC*HW)          // 1,310,720 elements per batch per map
#define KK 128
#define FEPS 1e-4f
#define FB2 64              // blocks per (batch, map) plane
#define NJ 10               // j-iterations; 2 float4 per array per thread per j

typedef float f4 __attribute__((ext_vector_type(4)));   // native vec for nt-load

// ws layout (floats):
// [m*48 + 0  + b]  A  (pos_loss / -ln2)
// [m*48 + 16 + b]  B  (neg_loss / -ln2)
// [m*48 + 32 + b]  n  (pos count)
// [96] off_tl [97] off_br [98] mask_sum [99] pull [100] push [104] ticket

__device__ __forceinline__ void proc(float tt, float xx,
                                     float& A, float& B, float& cnt)
{
    const float NLOG2E = -1.4426950408889634f;
    float z  = xx * NLOG2E;                 // -x*log2(e)
    float e  = exp2f(z);                    // e^-x          (v_exp_f32)
    float s  = 1.0f + e;
    float L  = __log2f(s);                  // log2(1+e^-x)  (v_log_f32)
    float p  = __builtin_amdgcn_rcpf(s);    // sigmoid(x)    (v_rcp_f32)
    float ep = e * p;                       // 1-p
    float a  = ep * ep * L;                 // (1-p)^2 * log2(1/p)
    float u  = 1.0f - tt;
    float u2 = u * u;
    float pw = p * u2;                      // p*(1-t)^2
    float bv = pw * pw * (L - z);           // (1-t)^4 p^2 log2(1/(1-p)); ==0 at t==1
    B += bv;
    bool pos = (tt == 1.0f);
    A   += pos ? a : 0.0f;
    cnt += pos ? 1.0f : 0.0f;
}

__global__ __launch_bounds__(256, 8) void focal_kernel(
    const float* __restrict__ t_tl, const float* __restrict__ t_br,
    const float* __restrict__ x_tl, const float* __restrict__ x_br,
    float* __restrict__ ws)
{
    const int m = blockIdx.z;
    const int b = blockIdx.y;
    const f4* __restrict__ T4 = (const f4*)((m ? t_br : t_tl) + (size_t)b * N1);
    const f4* __restrict__ X4 = (const f4*)((m ? x_br : x_tl) + (size_t)b * N1);

    const int JS = FB2 * 512;                       // 32768 float4 per j-step
    const int p0 = blockIdx.x * 512 + threadIdx.x;  // pos 0; pos 1 = p0+256

    // t: regular loads (L3-retained across replays; 2x84MB fits 256MB L3)
    // x: non-temporal (pure HBM stream, no L3 thrash)
    f4 ct0 = T4[p0];
    f4 cx0 = __builtin_nontemporal_load(X4 + p0);
    f4 ct1 = T4[p0 + 256];
    f4 cx1 = __builtin_nontemporal_load(X4 + p0 + 256);

    float A = 0.0f, B = 0.0f, cnt = 0.0f;
    #pragma unroll
    for (int j = 0; j < NJ; ++j) {
        f4 nt0, nx0, nt1, nx1;
        if (j + 1 < NJ) {
            const int q = p0 + (j + 1) * JS;
            nt0 = T4[q];
            nx0 = __builtin_nontemporal_load(X4 + q);
            nt1 = T4[q + 256];
            nx1 = __builtin_nontemporal_load(X4 + q + 256);
        }
        #pragma unroll
        for (int c = 0; c < 4; ++c) proc(ct0[c], cx0[c], A, B, cnt);
        #pragma unroll
        for (int c = 0; c < 4; ++c) proc(ct1[c], cx1[c], A, B, cnt);
        ct0 = nt0; cx0 = nx0; ct1 = nt1; cx1 = nx1;
    }

    #pragma unroll
    for (int off = 32; off > 0; off >>= 1) {
        A   += __shfl_down(A  , off, 64);
        B   += __shfl_down(B  , off, 64);
        cnt += __shfl_down(cnt, off, 64);
    }
    __shared__ float red[3][4];
    const int lane = threadIdx.x & 63, wv = threadIdx.x >> 6;
    if (lane == 0) { red[0][wv] = A; red[1][wv] = B; red[2][wv] = cnt; }
    __syncthreads();
    if (threadIdx.x == 0) {
        atomicAdd(&ws[m*48 +  0 + b], red[0][0] + red[0][1] + red[0][2] + red[0][3]);
        atomicAdd(&ws[m*48 + 16 + b], red[1][0] + red[1][1] + red[1][2] + red[1][3]);
        atomicAdd(&ws[m*48 + 32 + b], red[2][0] + red[2][1] + red[2][2] + red[2][3]);
    }
}

// off-loss + triplet fused; last finishing block also runs the finalize.
__global__ void small_kernel(
    const float* __restrict__ to_tl, const float* __restrict__ to_br,
    const float* __restrict__ po_tl, const float* __restrict__ po_br,
    const float* __restrict__ e_tl,  const float* __restrict__ e_br,
    const int* __restrict__ idx_tl,  const int* __restrict__ idx_br,
    const int* __restrict__ mask,    float* __restrict__ ws,
    float* __restrict__ out)
{
    const int b = blockIdx.x, k = threadIdx.x;
    const int lane = threadIdx.x & 63, wv = threadIdx.x >> 6;

    float mf = (float)mask[b*KK + k];
    const int itl = idx_tl[b*KK + k];
    const int ibr = idx_br[b*KK + k];

    // ---- offset loss partials ----
    float s_tl = 0.0f, s_br = 0.0f;
    #pragma unroll
    for (int ch = 0; ch < 2; ++ch) {
        float pv = po_tl[((size_t)b*2 + ch)*HW + itl];
        float tv = to_tl[(b*KK + k)*2 + ch];
        float d = pv - tv, ad = fabsf(d);
        s_tl += (ad < 1.0f) ? 0.5f*d*d : (ad - 0.5f);
        pv = po_br[((size_t)b*2 + ch)*HW + ibr];
        tv = to_br[(b*KK + k)*2 + ch];
        d = pv - tv; ad = fabsf(d);
        s_br += (ad < 1.0f) ? 0.5f*d*d : (ad - 0.5f);
    }
    s_tl *= mf; s_br *= mf;

    // ---- triplet ----
    __shared__ float ek_s[KK], mf_s[KK], nred[2];
    float tl = e_tl[(size_t)b*HW + itl];
    float br = e_br[(size_t)b*HW + ibr];
    float ek = 0.5f * (tl + br);
    ek_s[k] = ek; mf_s[k] = mf;

    float nm = mf;
    #pragma unroll
    for (int off = 32; off > 0; off >>= 1) nm += __shfl_down(nm, off, 64);
    if (lane == 0) nred[wv] = nm;
    __syncthreads();
    const float num  = nred[0] + nred[1];
    const float inv  = 1.0f / (num + FEPS);
    const float num2 = (num - 1.0f) * num;
    const float inv2 = 1.0f / (num2 + FEPS);

    float pull = ((tl-ek)*(tl-ek) + (br-ek)*(br-ek)) * inv * mf;

    float push = 0.0f;
    if (mf == 1.0f) {
        for (int j = 0; j < KK; ++j) {
            if (mf_s[j] == 1.0f) {
                float d = fabsf(ek_s[j] - ek);
                push += (fmaxf(2.0f - d, 0.0f) - 2.0f * inv) * inv2;
            }
        }
    }

    #pragma unroll
    for (int off = 32; off > 0; off >>= 1) {
        s_tl += __shfl_down(s_tl, off, 64);
        s_br += __shfl_down(s_br, off, 64);
        mf   += __shfl_down(mf  , off, 64);
        pull += __shfl_down(pull, off, 64);
        push += __shfl_down(push, off, 64);
    }
    __shared__ float r[5][2];
    __shared__ int last_flag;
    if (lane == 0) {
        r[0][wv] = s_tl; r[1][wv] = s_br; r[2][wv] = mf;
        r[3][wv] = pull; r[4][wv] = push;
    }
    __syncthreads();
    if (threadIdx.x == 0) {
        atomicAdd(&ws[96],  r[0][0] + r[0][1]);
        atomicAdd(&ws[97],  r[1][0] + r[1][1]);
        atomicAdd(&ws[98],  r[2][0] + r[2][1]);
        atomicAdd(&ws[99],  r[3][0] + r[3][1]);
        atomicAdd(&ws[100], r[4][0] + r[4][1]);
        __threadfence();
        unsigned old = atomicAdd((unsigned*)&ws[104], 1u);
        last_flag = (old == BB - 1) ? 1 : 0;
    }
    __syncthreads();

    if (last_flag) {
        // coherent read of all partials via atomic-read (cross-XCD safe)
        __shared__ float wsv[101];
        if (k < 101) wsv[k] = atomicAdd(&ws[k], 0.0f);
        __syncthreads();
        if (threadIdx.x == 0) {
            const float NLN2 = -0.6931471805599453f;
            float det = 0.0f;
            for (int m = 0; m < 2; ++m) {
                float f = 0.0f;
                for (int bb = 0; bb < BB; ++bb) {
                    float pos = NLN2 * wsv[m*48 +  0 + bb];
                    float neg = NLN2 * wsv[m*48 + 16 + bb];
                    float n   = wsv[m*48 + 32 + bb];
                    float per = (n == 0.0f) ? neg : (pos + neg) / n;
                    f -= per;
                }
                det += 0.5f * f;
            }
            float numoff = wsv[98] * 2.0f;
            float off = wsv[96] / (numoff + FEPS) + wsv[97] / (numoff + FEPS);
            out[0] = (det + wsv[99] + wsv[100] + off) / (float)BB;
        }
    }
}

extern "C" void kernel_launch(void* const* d_in, const int* in_sizes, int n_in,
                              void* d_out, int out_size, void* d_ws, size_t ws_size,
                              hipStream_t stream) {
    const float* t_tl  = (const float*)d_in[0];
    const float* t_br  = (const float*)d_in[1];
    const float* to_tl = (const float*)d_in[2];
    const float* to_br = (const float*)d_in[3];
    const float* x_tl  = (const float*)d_in[4];
    const float* x_br  = (const float*)d_in[5];
    const float* po_tl = (const float*)d_in[6];
    const float* po_br = (const float*)d_in[7];
    const float* e_tl  = (const float*)d_in[8];
    const float* e_br  = (const float*)d_in[9];
    const int* idx_tl  = (const int*)d_in[10];
    const int* idx_br  = (const int*)d_in[11];
    const int* mask    = (const int*)d_in[12];
    float* ws = (float*)d_ws;

    (void)hipMemsetAsync(ws, 0, 512, stream);
    focal_kernel<<<dim3(FB2, BB, 2), 256, 0, stream>>>(t_tl, t_br, x_tl, x_br, ws);
    small_kernel<<<BB, KK, 0, stream>>>(to_tl, to_br, po_tl, po_br, e_tl, e_br,
                                        idx_tl, idx_br, mask, ws, (float*)d_out);
}